// Round 2
// baseline (4483.685 us; speedup 1.0000x reference)
//
#include <hip/hip_runtime.h>
#include <cmath>

typedef __bf16 bf16;
typedef __bf16 bf16x8 __attribute__((ext_vector_type(8)));
typedef __bf16 bf16x4 __attribute__((ext_vector_type(4)));
typedef float  f32x4  __attribute__((ext_vector_type(4)));

#define MFMA16(a,b,c) __builtin_amdgcn_mfma_f32_16x16x32_bf16(a,b,c,0,0,0)

// async global->LDS, 16B per lane. LDS dest = wave-uniform base + lane*16.
__device__ __forceinline__ void async_ld16(const void* g, void* l) {
  __builtin_amdgcn_global_load_lds((__attribute__((address_space(1))) void*)(g),
                                   (__attribute__((address_space(3))) void*)(l),
                                   16, 0, 0);
}

enum { EPI_PATCH = 0, EPI_BF16 = 1, EPI_RESID = 2, EPI_GELU = 3 };

// C[M,N] = A[M,K] (bf16, row-major) * Wt[N,K]^T (bf16, row-major along K)
// 128x128 tile, BK=32, 4 waves, each wave 64x64 via 4x4 16x16x32 MFMA.
// blockIdx.z = split-K chunk (Kc elems); atomic epilogues add bias on z==0 only.
template <int EPI>
__global__ __launch_bounds__(256) void gemm_bt(
    const bf16* __restrict__ A, const bf16* __restrict__ Wt,
    const float* __restrict__ bias, bf16* __restrict__ outB,
    float* __restrict__ outF, int M, int N, int K, int Kc)
{
  __shared__ bf16 As[128 * 32];
  __shared__ bf16 Bs[128 * 32];
  const int tid  = threadIdx.x;
  const int lane = tid & 63, wid = tid >> 6;
  const int qr   = lane & 15, quad = lane >> 4;
  const int wm   = wid >> 1, wn = wid & 1;
  const int bm   = blockIdx.y, bn = blockIdx.x, z = blockIdx.z;
  const int kbeg = z * Kc;
  const int kend = min(K, kbeg + Kc);
  const int sr   = wid * 16 + (lane >> 2);  // staging row 0..63
  const int scol = (lane & 3) * 8;          // staging col (elems)

  f32x4 zero4 = {0.f, 0.f, 0.f, 0.f};
  f32x4 acc[4][4];
#pragma unroll
  for (int i = 0; i < 4; i++)
#pragma unroll
    for (int j = 0; j < 4; j++) acc[i][j] = zero4;

  const int r0a = min(bm * 128 + sr, M - 1);        // clamp ragged M
  const int r1a = min(bm * 128 + 64 + sr, M - 1);
  const size_t nr0 = (size_t)(bn * 128 + sr);
  const size_t nr1 = (size_t)(bn * 128 + 64 + sr);

  for (int k0 = kbeg; k0 < kend; k0 += 32) {
    __syncthreads();
    async_ld16(A  + (size_t)r0a * K + k0 + scol, &As[(wid * 16) * 32]);
    async_ld16(A  + (size_t)r1a * K + k0 + scol, &As[(64 + wid * 16) * 32]);
    async_ld16(Wt + nr0 * K + k0 + scol,         &Bs[(wid * 16) * 32]);
    async_ld16(Wt + nr1 * K + k0 + scol,         &Bs[(64 + wid * 16) * 32]);
    __syncthreads();
    bf16x8 af[4], bfr[4];
#pragma unroll
    for (int mi = 0; mi < 4; mi++)
      af[mi] = *(const bf16x8*)&As[(wm * 64 + mi * 16 + qr) * 32 + quad * 8];
#pragma unroll
    for (int ni = 0; ni < 4; ni++)
      bfr[ni] = *(const bf16x8*)&Bs[(wn * 64 + ni * 16 + qr) * 32 + quad * 8];
#pragma unroll
    for (int mi = 0; mi < 4; mi++)
#pragma unroll
      for (int ni = 0; ni < 4; ni++)
        acc[mi][ni] = MFMA16(af[mi], bfr[ni], acc[mi][ni]);
  }

  // epilogue: C row = quad*4+r, col = lane&15 within each 16x16 tile
#pragma unroll
  for (int mi = 0; mi < 4; mi++) {
#pragma unroll
    for (int ni = 0; ni < 4; ni++) {
      const int row0 = bm * 128 + wm * 64 + mi * 16 + quad * 4;
      const int col  = bn * 128 + wn * 64 + ni * 16 + qr;
      const float bv = (z == 0) ? bias[col] : 0.f;
#pragma unroll
      for (int r = 0; r < 4; r++) {
        const int row = row0 + r;
        if (row < M) {
          float v = acc[mi][ni][r] + bv;
          if constexpr (EPI == EPI_PATCH) {
            // row -> (b, patch n); accumulate into h[b*197 + 1 + n] (pos prefilled)
            int bb = row / 196, nn = row % 196;
            int orow = bb * 197 + 1 + nn;
            atomicAdd(&outF[(size_t)orow * 768 + col], v);
          } else if constexpr (EPI == EPI_BF16) {
            outB[(size_t)row * N + col] = (bf16)v;
          } else if constexpr (EPI == EPI_GELU) {
            float gel = 0.5f * v * (1.f + erff(v * 0.70710678118f));
            outB[(size_t)row * N + col] = (bf16)gel;
          } else {  // EPI_RESID: h += (acc + bias)
            atomicAdd(&outF[(size_t)row * 768 + col], v);
          }
        }
      }
    }
  }
}

// Attention: one block = (b, head, 64 q-rows). Full K/V in LDS. S=197, dh=64.
// P aliases K's LDS (K dead after scores) -> 67 KB -> 2 blocks/CU.
__global__ __launch_bounds__(256) void attn_kernel(
    const bf16* __restrict__ qkv, bf16* __restrict__ o)
{
  __shared__ __align__(16) char smem[68864];
  bf16 (*Qs)[72]  = (bf16(*)[72])(smem);                 //  9216 B
  bf16 (*Ks)[72]  = (bf16(*)[72])(smem + 9216);          // 29952 B
  bf16 (*Ps)[232] = (bf16(*)[232])(smem + 9216);         // aliases Ks (29696 B)
  bf16 (*Vt)[232] = (bf16(*)[232])(smem + 39168);        // 29696 B

  const int tid  = threadIdx.x;
  const int lane = tid & 63, wid = tid >> 6;
  const int qr   = lane & 15, quad = lane >> 4;
  const int qt   = blockIdx.x & 3, bh = blockIdx.x >> 2;
  const int head = bh % 12, b = bh / 12;
  const int q0   = qt * 64;
  const size_t base = (size_t)b * 197 * 2304 + head * 64;

  // stage Q (clamp rows >196 to 196; garbage rows never stored)
  {
    int r = tid >> 2, cb = (tid & 3) * 16;
    int s = q0 + r; if (s > 196) s = 196;
    const bf16* src = qkv + base + (size_t)s * 2304 + cb;
    *(uint4*)&Qs[r][cb]     = *(const uint4*)src;
    *(uint4*)&Qs[r][cb + 8] = *(const uint4*)(src + 8);
  }
  // stage K rows 0..207 (zeros >=197)
  for (int rr = tid >> 2; rr < 208; rr += 64) {
    int cb = (tid & 3) * 16;
    uint4 v0 = make_uint4(0, 0, 0, 0), v1 = make_uint4(0, 0, 0, 0);
    if (rr < 197) {
      const bf16* src = qkv + base + 768 + (size_t)rr * 2304 + cb;
      v0 = *(const uint4*)src; v1 = *(const uint4*)(src + 8);
    }
    *(uint4*)&Ks[rr][cb] = v0; *(uint4*)&Ks[rr][cb + 8] = v1;
  }
  // stage V transposed [d][key] (zeros for key>=197)
  for (int rr = tid >> 2; rr < 224; rr += 64) {
    int cb = (tid & 3) * 16;
    bf16 tmp[16];
    if (rr < 197) {
      const bf16* src = qkv + base + 1536 + (size_t)rr * 2304 + cb;
      *(uint4*)&tmp[0] = *(const uint4*)src;
      *(uint4*)&tmp[8] = *(const uint4*)(src + 8);
    } else {
#pragma unroll
      for (int j = 0; j < 16; j++) tmp[j] = (bf16)0.f;
    }
#pragma unroll
    for (int j = 0; j < 16; j++) Vt[cb + j][rr] = tmp[j];
  }
  __syncthreads();

  // scores: wave handles q rows [wid*16, wid*16+16)
  bf16x8 qa0 = *(const bf16x8*)&Qs[wid * 16 + qr][quad * 8];
  bf16x8 qa1 = *(const bf16x8*)&Qs[wid * 16 + qr][32 + quad * 8];
  f32x4 zero4 = {0.f, 0.f, 0.f, 0.f};
  f32x4 sc[13];
#pragma unroll
  for (int t = 0; t < 13; t++) sc[t] = zero4;
#pragma unroll
  for (int t = 0; t < 13; t++) {
    bf16x8 kb0 = *(const bf16x8*)&Ks[t * 16 + qr][quad * 8];
    bf16x8 kb1 = *(const bf16x8*)&Ks[t * 16 + qr][32 + quad * 8];
    sc[t] = MFMA16(qa0, kb0, sc[t]);
    sc[t] = MFMA16(qa1, kb1, sc[t]);
  }
  // softmax: lane holds col=16t+qr, row=quad*4+r; row-reduce across 16 lanes
  float mx[4] = {-1e30f, -1e30f, -1e30f, -1e30f};
#pragma unroll
  for (int t = 0; t < 13; t++) {
    bool valid = (t * 16 + qr) < 197;
#pragma unroll
    for (int r = 0; r < 4; r++) {
      float v = sc[t][r] * 0.125f;
      sc[t][r] = v;
      if (valid) mx[r] = fmaxf(mx[r], v);
    }
  }
#pragma unroll
  for (int r = 0; r < 4; r++)
#pragma unroll
    for (int off = 1; off < 16; off <<= 1)
      mx[r] = fmaxf(mx[r], __shfl_xor(mx[r], off, 16));
  float sum[4] = {0.f, 0.f, 0.f, 0.f};
#pragma unroll
  for (int t = 0; t < 13; t++) {
    bool valid = (t * 16 + qr) < 197;
#pragma unroll
    for (int r = 0; r < 4; r++) {
      float e = valid ? __expf(sc[t][r] - mx[r]) : 0.f;
      sc[t][r] = e; sum[r] += e;
    }
  }
#pragma unroll
  for (int r = 0; r < 4; r++) {
#pragma unroll
    for (int off = 1; off < 16; off <<= 1)
      sum[r] += __shfl_xor(sum[r], off, 16);
    sum[r] = 1.f / sum[r];
  }
  __syncthreads();   // all waves done reading Ks; safe to overwrite with Ps
#pragma unroll
  for (int t = 0; t < 13; t++)
#pragma unroll
    for (int r = 0; r < 4; r++)
      Ps[wid * 16 + quad * 4 + r][t * 16 + qr] = (bf16)(sc[t][r] * sum[r]);
  // zero Ps pad cols [208,224): wave covers its own 16 rows
  {
    bf16x4 zz = {(bf16)0.f, (bf16)0.f, (bf16)0.f, (bf16)0.f};
    *(bf16x4*)&Ps[wid * 16 + qr][208 + quad * 4] = zz;
  }
  __syncthreads();

  // PV: O[64 x 64] per wave-tile; K-loop over padded 224 keys
  f32x4 oa[4];
#pragma unroll
  for (int ni = 0; ni < 4; ni++) oa[ni] = zero4;
#pragma unroll
  for (int k0 = 0; k0 < 224; k0 += 32) {
    bf16x8 pa = *(const bf16x8*)&Ps[wid * 16 + qr][k0 + quad * 8];
#pragma unroll
    for (int ni = 0; ni < 4; ni++) {
      bf16x8 vb = *(const bf16x8*)&Vt[ni * 16 + qr][k0 + quad * 8];
      oa[ni] = MFMA16(pa, vb, oa[ni]);
    }
  }
  // store O at [b][s][head][d]
#pragma unroll
  for (int ni = 0; ni < 4; ni++)
#pragma unroll
    for (int r = 0; r < 4; r++) {
      int row = q0 + wid * 16 + quad * 4 + r;
      if (row < 197)
        o[(((size_t)b * 197 + row) * 12 + head) * 64 + ni * 16 + qr] =
            (bf16)oa[ni][r];
    }
}

// LayerNorm over 768, one wave per row, bf16 out
__global__ __launch_bounds__(256) void ln_bf16(
    const float* __restrict__ h, const float* __restrict__ w,
    const float* __restrict__ b, bf16* __restrict__ y, int rows)
{
  int row = blockIdx.x * 4 + (threadIdx.x >> 6);
  int lane = threadIdx.x & 63;
  if (row >= rows) return;
  const float* hr = h + (size_t)row * 768;
  float v[12]; float s = 0.f;
#pragma unroll
  for (int i = 0; i < 12; i++) { v[i] = hr[lane + 64 * i]; s += v[i]; }
#pragma unroll
  for (int off = 32; off >= 1; off >>= 1) s += __shfl_xor(s, off, 64);
  float mean = s * (1.f / 768.f);
  float q = 0.f;
#pragma unroll
  for (int i = 0; i < 12; i++) { float d = v[i] - mean; q += d * d; }
#pragma unroll
  for (int off = 32; off >= 1; off >>= 1) q += __shfl_xor(q, off, 64);
  float rstd = rsqrtf(q * (1.f / 768.f) + 1e-6f);
  bf16* yr = y + (size_t)row * 768;
#pragma unroll
  for (int i = 0; i < 12; i++)
    yr[lane + 64 * i] = (bf16)((v[i] - mean) * rstd * w[lane + 64 * i] + b[lane + 64 * i]);
}

// Final LN on the 32 CLS rows, fp32 out
__global__ __launch_bounds__(256) void ln_final(
    const float* __restrict__ h, const float* __restrict__ w,
    const float* __restrict__ b, float* __restrict__ out)
{
  int bi = blockIdx.x * 4 + (threadIdx.x >> 6);
  int lane = threadIdx.x & 63;
  if (bi >= 32) return;
  const float* hr = h + (size_t)bi * 197 * 768;
  float v[12]; float s = 0.f;
#pragma unroll
  for (int i = 0; i < 12; i++) { v[i] = hr[lane + 64 * i]; s += v[i]; }
#pragma unroll
  for (int off = 32; off >= 1; off >>= 1) s += __shfl_xor(s, off, 64);
  float mean = s * (1.f / 768.f);
  float q = 0.f;
#pragma unroll
  for (int i = 0; i < 12; i++) { float d = v[i] - mean; q += d * d; }
#pragma unroll
  for (int off = 32; off >= 1; off >>= 1) q += __shfl_xor(q, off, 64);
  float rstd = rsqrtf(q * (1.f / 768.f) + 1e-6f);
#pragma unroll
  for (int i = 0; i < 12; i++)
    out[(size_t)bi * 768 + lane + 64 * i] =
        (v[i] - mean) * rstd * w[lane + 64 * i] + b[lane + 64 * i];
}

// [z][R][C] fp32 -> [z][C][R] bf16 (all dims multiples of 32)
__global__ __launch_bounds__(256) void transpose_w(
    const float* __restrict__ in, bf16* __restrict__ out, int R, int C)
{
  __shared__ float t[32][33];
  size_t zoff = (size_t)blockIdx.z * R * C;
  in += zoff; out += zoff;
  int c0 = blockIdx.x * 32, r0 = blockIdx.y * 32;
  int lx = threadIdx.x & 31, ly = threadIdx.x >> 5;  // 32 x 8
#pragma unroll
  for (int i = 0; i < 32; i += 8) t[ly + i][lx] = in[(size_t)(r0 + ly + i) * C + c0 + lx];
  __syncthreads();
#pragma unroll
  for (int i = 0; i < 32; i += 8)
    out[(size_t)(c0 + ly + i) * R + r0 + lx] = (bf16)t[lx][ly + i];
}

__global__ __launch_bounds__(256) void convert_bf16(
    const float* __restrict__ in, bf16* __restrict__ out, int n)
{
  int i = blockIdx.x * 256 + threadIdx.x;
  if (i < n) out[i] = (bf16)in[i];
}

// x(32,3,224,224) -> patches[6272][768] bf16; k = c*256 + iy*16 + ix
__global__ __launch_bounds__(256) void patch_extract(
    const float* __restrict__ x, bf16* __restrict__ patches)
{
  int i = blockIdx.x * 256 + threadIdx.x;
  if (i >= 6272 * 192) return;
  int m = i / 192, kq = (i % 192) * 4;
  int b = m / 196, pp = m % 196, py = pp / 14, px = pp % 14;
  int c = kq >> 8, rem = kq & 255, iy = rem >> 4, ix = rem & 15;
  const float4 v = *(const float4*)&x[(((size_t)(b * 3 + c) * 224 + py * 16 + iy) * 224) + px * 16 + ix];
  bf16x4 pv = {(bf16)v.x, (bf16)v.y, (bf16)v.z, (bf16)v.w};
  *(bf16x4*)&patches[(size_t)m * 768 + kq] = pv;
}

// prefill h: h[b][s][:] = pos[s] (+ cls for s==0); patch GEMM then accumulates
__global__ __launch_bounds__(256) void h_init_full(
    const float* __restrict__ cls, const float* __restrict__ pos,
    float* __restrict__ h)
{
  int i = blockIdx.x * 256 + threadIdx.x;
  if (i >= 6304 * 192) return;
  int row = i / 192, c4 = (i % 192) * 4;
  int s = row % 197;
  float4 pv = *(const float4*)&pos[(size_t)s * 768 + c4];
  if (s == 0) {
    float4 cv = *(const float4*)&cls[c4];
    pv.x += cv.x; pv.y += cv.y; pv.z += cv.z; pv.w += cv.w;
  }
  *(float4*)&h[(size_t)row * 768 + c4] = pv;
}

extern "C" void kernel_launch(void* const* d_in, const int* in_sizes, int n_in,
                              void* d_out, int out_size, void* d_ws, size_t ws_size,
                              hipStream_t stream)
{
  const float* x      = (const float*)d_in[0];
  const float* conv_w = (const float*)d_in[1];
  const float* conv_b = (const float*)d_in[2];
  const float* cls    = (const float*)d_in[3];
  const float* pos    = (const float*)d_in[4];
  const float* ln1_w  = (const float*)d_in[5];
  const float* ln1_b  = (const float*)d_in[6];
  const float* qkv_w  = (const float*)d_in[7];
  const float* qkv_b  = (const float*)d_in[8];
  const float* proj_w = (const float*)d_in[9];
  const float* proj_b = (const float*)d_in[10];
  const float* ln2_w  = (const float*)d_in[11];
  const float* ln2_b  = (const float*)d_in[12];
  const float* fc1_w  = (const float*)d_in[13];
  const float* fc1_b  = (const float*)d_in[14];
  const float* fc2_w  = (const float*)d_in[15];
  const float* fc2_b  = (const float*)d_in[16];
  const float* lnf_w  = (const float*)d_in[17];
  const float* lnf_b  = (const float*)d_in[18];
  float* out = (float*)d_out;
  (void)in_sizes; (void)n_in; (void)out_size; (void)ws_size;

  char* ws = (char*)d_ws;
  size_t off = 0;
  auto alloc = [&](size_t bytes) -> char* {
    char* p = ws + off;
    off += (bytes + 255) & ~(size_t)255;
    return p;
  };

  bf16*  convwB  = (bf16*)alloc((size_t)768 * 768 * 2);
  bf16*  qkvT    = (bf16*)alloc((size_t)12 * 2304 * 768 * 2);
  bf16*  projT   = (bf16*)alloc((size_t)12 * 768 * 768 * 2);
  bf16*  fc1T    = (bf16*)alloc((size_t)12 * 3072 * 768 * 2);
  bf16*  fc2T    = (bf16*)alloc((size_t)12 * 768 * 3072 * 2);
  bf16*  patches = (bf16*)alloc((size_t)6272 * 768 * 2);
  float* h       = (float*)alloc((size_t)6304 * 768 * 4);
  bf16*  y       = (bf16*)alloc((size_t)6304 * 768 * 2);
  bf16*  qkvB    = (bf16*)alloc((size_t)6304 * 2304 * 2);
  bf16*  obuf    = (bf16*)alloc((size_t)6304 * 768 * 2);
  bf16*  g       = (bf16*)alloc((size_t)6304 * 3072 * 2);

  // weight prep (every call: ws is re-poisoned)
  convert_bf16<<<(768 * 768 + 255) / 256, 256, 0, stream>>>(conv_w, convwB, 768 * 768);
  transpose_w<<<dim3(2304 / 32, 768 / 32, 12), 256, 0, stream>>>(qkv_w, qkvT, 768, 2304);
  transpose_w<<<dim3(768 / 32, 768 / 32, 12), 256, 0, stream>>>(proj_w, projT, 768, 768);
  transpose_w<<<dim3(3072 / 32, 768 / 32, 12), 256, 0, stream>>>(fc1_w, fc1T, 768, 3072);
  transpose_w<<<dim3(768 / 32, 3072 / 32, 12), 256, 0, stream>>>(fc2_w, fc2T, 3072, 768);

  patch_extract<<<(6272 * 192) / 256, 256, 0, stream>>>(x, patches);
  h_init_full<<<(6304 * 192 + 255) / 256, 256, 0, stream>>>(cls, pos, h);
  gemm_bt<EPI_PATCH><<<dim3(6, 49, 2), 256, 0, stream>>>(
      patches, convwB, conv_b, nullptr, h, 6272, 768, 768, 384);

  for (int l = 0; l < 12; l++) {
    ln_bf16<<<1576, 256, 0, stream>>>(h, ln1_w + l * 768, ln1_b + l * 768, y, 6304);
    gemm_bt<EPI_BF16><<<dim3(18, 50, 1), 256, 0, stream>>>(
        y, qkvT + (size_t)l * 2304 * 768, qkv_b + l * 2304, qkvB, nullptr,
        6304, 2304, 768, 768);
    attn_kernel<<<32 * 12 * 4, 256, 0, stream>>>(qkvB, obuf);
    gemm_bt<EPI_RESID><<<dim3(6, 50, 2), 256, 0, stream>>>(
        obuf, projT + (size_t)l * 768 * 768, proj_b + l * 768, nullptr, h,
        6304, 768, 768, 384);
    ln_bf16<<<1576, 256, 0, stream>>>(h, ln2_w + l * 768, ln2_b + l * 768, y, 6304);
    gemm_bt<EPI_GELU><<<dim3(24, 50, 1), 256, 0, stream>>>(
        y, fc1T + (size_t)l * 3072 * 768, fc1_b + l * 3072, g, nullptr,
        6304, 3072, 768, 768);
    gemm_bt<EPI_RESID><<<dim3(6, 50, 4), 256, 0, stream>>>(
        g, fc2T + (size_t)l * 768 * 3072, fc2_b + l * 768, nullptr, h,
        6304, 768, 3072, 768);
  }
  ln_final<<<8, 256, 0, stream>>>(h, lnf_w, lnf_b, out);
}

// Round 3
// 4080.801 us; speedup vs baseline: 1.0987x; 1.0987x over previous
//
#include <hip/hip_runtime.h>
#include <cmath>

typedef __bf16 bf16;
typedef __bf16 bf16x8 __attribute__((ext_vector_type(8)));
typedef __bf16 bf16x4 __attribute__((ext_vector_type(4)));
typedef float  f32x4  __attribute__((ext_vector_type(4)));

#define MFMA16(a,b,c) __builtin_amdgcn_mfma_f32_16x16x32_bf16(a,b,c,0,0,0)

// async global->LDS, 16B per lane. LDS dest = wave-uniform base + lane*16.
__device__ __forceinline__ void async_ld16(const void* g, void* l) {
  __builtin_amdgcn_global_load_lds((__attribute__((address_space(1))) void*)(g),
                                   (__attribute__((address_space(3))) void*)(l),
                                   16, 0, 0);
}

enum { EPI_PATCH = 0, EPI_BF16 = 1, EPI_RESID = 2, EPI_GELU = 3 };

// C[M,N] = A[M,K] (bf16, row-major) * Wt[N,K]^T (bf16, row-major along K)
// TM x 128 tile, BK=32, 4 waves. TM=128: wave=64x64 (4x4 MFMA tiles);
// TM=64: wave=32x64 (2x4). blockIdx.x=bm (fast; consecutive ids share B-tile
// for XCD-L2 reuse), blockIdx.y=bn, blockIdx.z=split-K chunk of Kc elems.
template <int EPI, int TM>
__global__ __launch_bounds__(256) void gemm_bt(
    const bf16* __restrict__ A, const bf16* __restrict__ Wt,
    const float* __restrict__ bias, bf16* __restrict__ outB,
    float* __restrict__ outF, int M, int N, int K, int Kc)
{
  constexpr int MI = TM / 32;          // m-tiles per wave (4 or 2)
  __shared__ bf16 As[TM * 32];
  __shared__ bf16 Bs[128 * 32];
  const int tid  = threadIdx.x;
  const int lane = tid & 63, wid = tid >> 6;
  const int qr   = lane & 15, quad = lane >> 4;
  const int wm   = wid >> 1, wn = wid & 1;
  const int bm   = blockIdx.x, bn = blockIdx.y, z = blockIdx.z;
  const int kbeg = z * Kc;
  const int kend = min(K, kbeg + Kc);
  const int sr   = wid * 16 + (lane >> 2);  // staging row 0..63
  const int scol = (lane & 3) * 8;          // staging col (elems)

  f32x4 zero4 = {0.f, 0.f, 0.f, 0.f};
  f32x4 acc[MI][4];
#pragma unroll
  for (int i = 0; i < MI; i++)
#pragma unroll
    for (int j = 0; j < 4; j++) acc[i][j] = zero4;

  int ra[TM / 64];
#pragma unroll
  for (int s = 0; s < TM / 64; s++)
    ra[s] = min(bm * TM + s * 64 + sr, M - 1);      // clamp ragged M
  const size_t nr0 = (size_t)(bn * 128 + sr);
  const size_t nr1 = (size_t)(bn * 128 + 64 + sr);

  for (int k0 = kbeg; k0 < kend; k0 += 32) {
    __syncthreads();
#pragma unroll
    for (int s = 0; s < TM / 64; s++)
      async_ld16(A + (size_t)ra[s] * K + k0 + scol, &As[(s * 64 + wid * 16) * 32]);
    async_ld16(Wt + nr0 * K + k0 + scol, &Bs[(wid * 16) * 32]);
    async_ld16(Wt + nr1 * K + k0 + scol, &Bs[(64 + wid * 16) * 32]);
    __syncthreads();
    bf16x8 af[MI], bfr[4];
#pragma unroll
    for (int mi = 0; mi < MI; mi++)
      af[mi] = *(const bf16x8*)&As[(wm * (MI * 16) + mi * 16 + qr) * 32 + quad * 8];
#pragma unroll
    for (int ni = 0; ni < 4; ni++)
      bfr[ni] = *(const bf16x8*)&Bs[(wn * 64 + ni * 16 + qr) * 32 + quad * 8];
#pragma unroll
    for (int mi = 0; mi < MI; mi++)
#pragma unroll
      for (int ni = 0; ni < 4; ni++)
        acc[mi][ni] = MFMA16(af[mi], bfr[ni], acc[mi][ni]);
  }

  // epilogue: C row = quad*4+r, col = lane&15 within each 16x16 tile
#pragma unroll
  for (int mi = 0; mi < MI; mi++) {
#pragma unroll
    for (int ni = 0; ni < 4; ni++) {
      const int row0 = bm * TM + wm * (MI * 16) + mi * 16 + quad * 4;
      const int col  = bn * 128 + wn * 64 + ni * 16 + qr;
      const float bv = (z == 0) ? bias[col] : 0.f;
#pragma unroll
      for (int r = 0; r < 4; r++) {
        const int row = row0 + r;
        if (row < M) {
          float v = acc[mi][ni][r] + bv;
          if constexpr (EPI == EPI_PATCH) {
            // row -> (b, patch n); accumulate into h[b*197 + 1 + n] (pos prefilled)
            int bb = row / 196, nn = row % 196;
            int orow = bb * 197 + 1 + nn;
            atomicAdd(&outF[(size_t)orow * 768 + col], v);
          } else if constexpr (EPI == EPI_BF16) {
            outB[(size_t)row * N + col] = (bf16)v;
          } else if constexpr (EPI == EPI_GELU) {
            float gel = 0.5f * v * (1.f + erff(v * 0.70710678118f));
            outB[(size_t)row * N + col] = (bf16)gel;
          } else {  // EPI_RESID: h += (acc + bias)
            atomicAdd(&outF[(size_t)row * 768 + col], v);
          }
        }
      }
    }
  }
}

// Attention: one block = (b, head, 64 q-rows). Full K/V in LDS. S=197, dh=64.
// P aliases K's LDS (K dead after scores) -> 67 KB -> 2 blocks/CU.
__global__ __launch_bounds__(256) void attn_kernel(
    const bf16* __restrict__ qkv, bf16* __restrict__ o)
{
  __shared__ __align__(16) char smem[68864];
  bf16 (*Qs)[72]  = (bf16(*)[72])(smem);                 //  9216 B
  bf16 (*Ks)[72]  = (bf16(*)[72])(smem + 9216);          // 29952 B
  bf16 (*Ps)[232] = (bf16(*)[232])(smem + 9216);         // aliases Ks (29696 B)
  bf16 (*Vt)[232] = (bf16(*)[232])(smem + 39168);        // 29696 B

  const int tid  = threadIdx.x;
  const int lane = tid & 63, wid = tid >> 6;
  const int qr   = lane & 15, quad = lane >> 4;
  const int qt   = blockIdx.x & 3, bh = blockIdx.x >> 2;
  const int head = bh % 12, b = bh / 12;
  const int q0   = qt * 64;
  const size_t base = (size_t)b * 197 * 2304 + head * 64;

  // stage Q (clamp rows >196 to 196; garbage rows never stored)
  {
    int r = tid >> 2, cb = (tid & 3) * 16;
    int s = q0 + r; if (s > 196) s = 196;
    const bf16* src = qkv + base + (size_t)s * 2304 + cb;
    *(uint4*)&Qs[r][cb]     = *(const uint4*)src;
    *(uint4*)&Qs[r][cb + 8] = *(const uint4*)(src + 8);
  }
  // stage K rows 0..207 (zeros >=197)
  for (int rr = tid >> 2; rr < 208; rr += 64) {
    int cb = (tid & 3) * 16;
    uint4 v0 = make_uint4(0, 0, 0, 0), v1 = make_uint4(0, 0, 0, 0);
    if (rr < 197) {
      const bf16* src = qkv + base + 768 + (size_t)rr * 2304 + cb;
      v0 = *(const uint4*)src; v1 = *(const uint4*)(src + 8);
    }
    *(uint4*)&Ks[rr][cb] = v0; *(uint4*)&Ks[rr][cb + 8] = v1;
  }
  // stage V transposed [d][key] (zeros for key>=197)
  for (int rr = tid >> 2; rr < 224; rr += 64) {
    int cb = (tid & 3) * 16;
    bf16 tmp[16];
    if (rr < 197) {
      const bf16* src = qkv + base + 1536 + (size_t)rr * 2304 + cb;
      *(uint4*)&tmp[0] = *(const uint4*)src;
      *(uint4*)&tmp[8] = *(const uint4*)(src + 8);
    } else {
#pragma unroll
      for (int j = 0; j < 16; j++) tmp[j] = (bf16)0.f;
    }
#pragma unroll
    for (int j = 0; j < 16; j++) Vt[cb + j][rr] = tmp[j];
  }
  __syncthreads();

  // scores: wave handles q rows [wid*16, wid*16+16)
  bf16x8 qa0 = *(const bf16x8*)&Qs[wid * 16 + qr][quad * 8];
  bf16x8 qa1 = *(const bf16x8*)&Qs[wid * 16 + qr][32 + quad * 8];
  f32x4 zero4 = {0.f, 0.f, 0.f, 0.f};
  f32x4 sc[13];
#pragma unroll
  for (int t = 0; t < 13; t++) sc[t] = zero4;
#pragma unroll
  for (int t = 0; t < 13; t++) {
    bf16x8 kb0 = *(const bf16x8*)&Ks[t * 16 + qr][quad * 8];
    bf16x8 kb1 = *(const bf16x8*)&Ks[t * 16 + qr][32 + quad * 8];
    sc[t] = MFMA16(qa0, kb0, sc[t]);
    sc[t] = MFMA16(qa1, kb1, sc[t]);
  }
  // softmax: lane holds col=16t+qr, row=quad*4+r; row-reduce across 16 lanes
  float mx[4] = {-1e30f, -1e30f, -1e30f, -1e30f};
#pragma unroll
  for (int t = 0; t < 13; t++) {
    bool valid = (t * 16 + qr) < 197;
#pragma unroll
    for (int r = 0; r < 4; r++) {
      float v = sc[t][r] * 0.125f;
      sc[t][r] = v;
      if (valid) mx[r] = fmaxf(mx[r], v);
    }
  }
#pragma unroll
  for (int r = 0; r < 4; r++)
#pragma unroll
    for (int off = 1; off < 16; off <<= 1)
      mx[r] = fmaxf(mx[r], __shfl_xor(mx[r], off, 16));
  float sum[4] = {0.f, 0.f, 0.f, 0.f};
#pragma unroll
  for (int t = 0; t < 13; t++) {
    bool valid = (t * 16 + qr) < 197;
#pragma unroll
    for (int r = 0; r < 4; r++) {
      float e = valid ? __expf(sc[t][r] - mx[r]) : 0.f;
      sc[t][r] = e; sum[r] += e;
    }
  }
#pragma unroll
  for (int r = 0; r < 4; r++) {
#pragma unroll
    for (int off = 1; off < 16; off <<= 1)
      sum[r] += __shfl_xor(sum[r], off, 16);
    sum[r] = 1.f / sum[r];
  }
  __syncthreads();   // all waves done reading Ks; safe to overwrite with Ps
#pragma unroll
  for (int t = 0; t < 13; t++)
#pragma unroll
    for (int r = 0; r < 4; r++)
      Ps[wid * 16 + quad * 4 + r][t * 16 + qr] = (bf16)(sc[t][r] * sum[r]);
  // zero Ps pad cols [208,224): wave covers its own 16 rows
  {
    bf16x4 zz = {(bf16)0.f, (bf16)0.f, (bf16)0.f, (bf16)0.f};
    *(bf16x4*)&Ps[wid * 16 + qr][208 + quad * 4] = zz;
  }
  __syncthreads();

  // PV: O[64 x 64] per wave-tile; K-loop over padded 224 keys
  f32x4 oa[4];
#pragma unroll
  for (int ni = 0; ni < 4; ni++) oa[ni] = zero4;
#pragma unroll
  for (int k0 = 0; k0 < 224; k0 += 32) {
    bf16x8 pa = *(const bf16x8*)&Ps[wid * 16 + qr][k0 + quad * 8];
#pragma unroll
    for (int ni = 0; ni < 4; ni++) {
      bf16x8 vb = *(const bf16x8*)&Vt[ni * 16 + qr][k0 + quad * 8];
      oa[ni] = MFMA16(pa, vb, oa[ni]);
    }
  }
  // store O at [b][s][head][d]
#pragma unroll
  for (int ni = 0; ni < 4; ni++)
#pragma unroll
    for (int r = 0; r < 4; r++) {
      int row = q0 + wid * 16 + quad * 4 + r;
      if (row < 197)
        o[(((size_t)b * 197 + row) * 12 + head) * 64 + ni * 16 + qr] =
            (bf16)oa[ni][r];
    }
}

// LayerNorm over 768, one wave per row, bf16 out
__global__ __launch_bounds__(256) void ln_bf16(
    const float* __restrict__ h, const float* __restrict__ w,
    const float* __restrict__ b, bf16* __restrict__ y, int rows)
{
  int row = blockIdx.x * 4 + (threadIdx.x >> 6);
  int lane = threadIdx.x & 63;
  if (row >= rows) return;
  const float* hr = h + (size_t)row * 768;
  float v[12]; float s = 0.f;
#pragma unroll
  for (int i = 0; i < 12; i++) { v[i] = hr[lane + 64 * i]; s += v[i]; }
#pragma unroll
  for (int off = 32; off >= 1; off >>= 1) s += __shfl_xor(s, off, 64);
  float mean = s * (1.f / 768.f);
  float q = 0.f;
#pragma unroll
  for (int i = 0; i < 12; i++) { float d = v[i] - mean; q += d * d; }
#pragma unroll
  for (int off = 32; off >= 1; off >>= 1) q += __shfl_xor(q, off, 64);
  float rstd = rsqrtf(q * (1.f / 768.f) + 1e-6f);
  bf16* yr = y + (size_t)row * 768;
#pragma unroll
  for (int i = 0; i < 12; i++)
    yr[lane + 64 * i] = (bf16)((v[i] - mean) * rstd * w[lane + 64 * i] + b[lane + 64 * i]);
}

// Final LN on the 32 CLS rows, fp32 out
__global__ __launch_bounds__(256) void ln_final(
    const float* __restrict__ h, const float* __restrict__ w,
    const float* __restrict__ b, float* __restrict__ out)
{
  int bi = blockIdx.x * 4 + (threadIdx.x >> 6);
  int lane = threadIdx.x & 63;
  if (bi >= 32) return;
  const float* hr = h + (size_t)bi * 197 * 768;
  float v[12]; float s = 0.f;
#pragma unroll
  for (int i = 0; i < 12; i++) { v[i] = hr[lane + 64 * i]; s += v[i]; }
#pragma unroll
  for (int off = 32; off >= 1; off >>= 1) s += __shfl_xor(s, off, 64);
  float mean = s * (1.f / 768.f);
  float q = 0.f;
#pragma unroll
  for (int i = 0; i < 12; i++) { float d = v[i] - mean; q += d * d; }
#pragma unroll
  for (int off = 32; off >= 1; off >>= 1) q += __shfl_xor(q, off, 64);
  float rstd = rsqrtf(q * (1.f / 768.f) + 1e-6f);
#pragma unroll
  for (int i = 0; i < 12; i++)
    out[(size_t)bi * 768 + lane + 64 * i] =
        (v[i] - mean) * rstd * w[lane + 64 * i] + b[lane + 64 * i];
}

// [z][R][C] fp32 -> [z][C][R] bf16 (all dims multiples of 32)
__global__ __launch_bounds__(256) void transpose_w(
    const float* __restrict__ in, bf16* __restrict__ out, int R, int C)
{
  __shared__ float t[32][33];
  size_t zoff = (size_t)blockIdx.z * R * C;
  in += zoff; out += zoff;
  int c0 = blockIdx.x * 32, r0 = blockIdx.y * 32;
  int lx = threadIdx.x & 31, ly = threadIdx.x >> 5;  // 32 x 8
#pragma unroll
  for (int i = 0; i < 32; i += 8) t[ly + i][lx] = in[(size_t)(r0 + ly + i) * C + c0 + lx];
  __syncthreads();
#pragma unroll
  for (int i = 0; i < 32; i += 8)
    out[(size_t)(c0 + ly + i) * R + r0 + lx] = (bf16)t[lx][ly + i];
}

__global__ __launch_bounds__(256) void convert_bf16(
    const float* __restrict__ in, bf16* __restrict__ out, int n)
{
  int i = blockIdx.x * 256 + threadIdx.x;
  if (i < n) out[i] = (bf16)in[i];
}

// x(32,3,224,224) -> patches[6272][768] bf16; k = c*256 + iy*16 + ix
__global__ __launch_bounds__(256) void patch_extract(
    const float* __restrict__ x, bf16* __restrict__ patches)
{
  int i = blockIdx.x * 256 + threadIdx.x;
  if (i >= 6272 * 192) return;
  int m = i / 192, kq = (i % 192) * 4;
  int b = m / 196, pp = m % 196, py = pp / 14, px = pp % 14;
  int c = kq >> 8, rem = kq & 255, iy = rem >> 4, ix = rem & 15;
  const float4 v = *(const float4*)&x[(((size_t)(b * 3 + c) * 224 + py * 16 + iy) * 224) + px * 16 + ix];
  bf16x4 pv = {(bf16)v.x, (bf16)v.y, (bf16)v.z, (bf16)v.w};
  *(bf16x4*)&patches[(size_t)m * 768 + kq] = pv;
}

// prefill h: h[b][s][:] = pos[s] (+ cls for s==0); patch GEMM then accumulates
__global__ __launch_bounds__(256) void h_init_full(
    const float* __restrict__ cls, const float* __restrict__ pos,
    float* __restrict__ h)
{
  int i = blockIdx.x * 256 + threadIdx.x;
  if (i >= 6304 * 192) return;
  int row = i / 192, c4 = (i % 192) * 4;
  int s = row % 197;
  float4 pv = *(const float4*)&pos[(size_t)s * 768 + c4];
  if (s == 0) {
    float4 cv = *(const float4*)&cls[c4];
    pv.x += cv.x; pv.y += cv.y; pv.z += cv.z; pv.w += cv.w;
  }
  *(float4*)&h[(size_t)row * 768 + c4] = pv;
}

extern "C" void kernel_launch(void* const* d_in, const int* in_sizes, int n_in,
                              void* d_out, int out_size, void* d_ws, size_t ws_size,
                              hipStream_t stream)
{
  const float* x      = (const float*)d_in[0];
  const float* conv_w = (const float*)d_in[1];
  const float* conv_b = (const float*)d_in[2];
  const float* cls    = (const float*)d_in[3];
  const float* pos    = (const float*)d_in[4];
  const float* ln1_w  = (const float*)d_in[5];
  const float* ln1_b  = (const float*)d_in[6];
  const float* qkv_w  = (const float*)d_in[7];
  const float* qkv_b  = (const float*)d_in[8];
  const float* proj_w = (const float*)d_in[9];
  const float* proj_b = (const float*)d_in[10];
  const float* ln2_w  = (const float*)d_in[11];
  const float* ln2_b  = (const float*)d_in[12];
  const float* fc1_w  = (const float*)d_in[13];
  const float* fc1_b  = (const float*)d_in[14];
  const float* fc2_w  = (const float*)d_in[15];
  const float* fc2_b  = (const float*)d_in[16];
  const float* lnf_w  = (const float*)d_in[17];
  const float* lnf_b  = (const float*)d_in[18];
  float* out = (float*)d_out;
  (void)in_sizes; (void)n_in; (void)out_size; (void)ws_size;

  char* ws = (char*)d_ws;
  size_t off = 0;
  auto alloc = [&](size_t bytes) -> char* {
    char* p = ws + off;
    off += (bytes + 255) & ~(size_t)255;
    return p;
  };

  bf16*  convwB  = (bf16*)alloc((size_t)768 * 768 * 2);
  bf16*  qkvT    = (bf16*)alloc((size_t)12 * 2304 * 768 * 2);
  bf16*  projT   = (bf16*)alloc((size_t)12 * 768 * 768 * 2);
  bf16*  fc1T    = (bf16*)alloc((size_t)12 * 3072 * 768 * 2);
  bf16*  fc2T    = (bf16*)alloc((size_t)12 * 768 * 3072 * 2);
  bf16*  patches = (bf16*)alloc((size_t)6272 * 768 * 2);
  float* h       = (float*)alloc((size_t)6304 * 768 * 4);
  bf16*  y       = (bf16*)alloc((size_t)6304 * 768 * 2);
  bf16*  qkvB    = (bf16*)alloc((size_t)6304 * 2304 * 2);
  bf16*  obuf    = (bf16*)alloc((size_t)6304 * 768 * 2);
  bf16*  g       = (bf16*)alloc((size_t)6304 * 3072 * 2);

  // weight prep (every call: ws is re-poisoned)
  convert_bf16<<<(768 * 768 + 255) / 256, 256, 0, stream>>>(conv_w, convwB, 768 * 768);
  transpose_w<<<dim3(2304 / 32, 768 / 32, 12), 256, 0, stream>>>(qkv_w, qkvT, 768, 2304);
  transpose_w<<<dim3(768 / 32, 768 / 32, 12), 256, 0, stream>>>(proj_w, projT, 768, 768);
  transpose_w<<<dim3(3072 / 32, 768 / 32, 12), 256, 0, stream>>>(fc1_w, fc1T, 768, 3072);
  transpose_w<<<dim3(768 / 32, 3072 / 32, 12), 256, 0, stream>>>(fc2_w, fc2T, 3072, 768);

  patch_extract<<<(6272 * 192) / 256, 256, 0, stream>>>(x, patches);
  h_init_full<<<(6304 * 192 + 255) / 256, 256, 0, stream>>>(cls, pos, h);
  gemm_bt<EPI_PATCH, 64><<<dim3(98, 6, 1), 256, 0, stream>>>(
      patches, convwB, conv_b, nullptr, h, 6272, 768, 768, 768);

  for (int l = 0; l < 12; l++) {
    ln_bf16<<<1576, 256, 0, stream>>>(h, ln1_w + l * 768, ln1_b + l * 768, y, 6304);
    gemm_bt<EPI_BF16, 128><<<dim3(50, 18, 1), 256, 0, stream>>>(
        y, qkvT + (size_t)l * 2304 * 768, qkv_b + l * 2304, qkvB, nullptr,
        6304, 2304, 768, 768);
    attn_kernel<<<32 * 12 * 4, 256, 0, stream>>>(qkvB, obuf);
    gemm_bt<EPI_RESID, 64><<<dim3(99, 6, 1), 256, 0, stream>>>(
        obuf, projT + (size_t)l * 768 * 768, proj_b + l * 768, nullptr, h,
        6304, 768, 768, 768);
    ln_bf16<<<1576, 256, 0, stream>>>(h, ln2_w + l * 768, ln2_b + l * 768, y, 6304);
    gemm_bt<EPI_GELU, 128><<<dim3(50, 24, 1), 256, 0, stream>>>(
        y, fc1T + (size_t)l * 3072 * 768, fc1_b + l * 3072, g, nullptr,
        6304, 3072, 768, 768);
    gemm_bt<EPI_RESID, 64><<<dim3(99, 6, 2), 256, 0, stream>>>(
        g, fc2T + (size_t)l * 768 * 3072, fc2_b + l * 768, nullptr, h,
        6304, 768, 3072, 1536);
  }
  ln_final<<<8, 256, 0, stream>>>(h, lnf_w, lnf_b, out);
}

// Round 4
// 3709.531 us; speedup vs baseline: 1.2087x; 1.1001x over previous
//
#include <hip/hip_runtime.h>
#include <cmath>

typedef __bf16 bf16;
typedef __bf16 bf16x8 __attribute__((ext_vector_type(8)));
typedef __bf16 bf16x4 __attribute__((ext_vector_type(4)));
typedef float  f32x4  __attribute__((ext_vector_type(4)));

#define MFMA16(a,b,c) __builtin_amdgcn_mfma_f32_16x16x32_bf16(a,b,c,0,0,0)

// async global->LDS, 16B per lane. LDS dest = wave-uniform base + lane*16.
__device__ __forceinline__ void async_ld16(const void* g, void* l) {
  __builtin_amdgcn_global_load_lds((__attribute__((address_space(1))) void*)(g),
                                   (__attribute__((address_space(3))) void*)(l),
                                   16, 0, 0);
}

enum { EPI_PATCH = 0, EPI_BF16 = 1, EPI_RESID = 2, EPI_GELU = 3 };

// ---------------- 4-wave, TM x 128 (TM=64 for narrow-N / split-K) -----------
template <int EPI, int TM>
__global__ __launch_bounds__(256) void gemm_bt(
    const bf16* __restrict__ A, const bf16* __restrict__ Wt,
    const float* __restrict__ bias, bf16* __restrict__ outB,
    float* __restrict__ outF, int M, int N, int K, int Kc)
{
  constexpr int MI = TM / 32;          // m-tiles per wave (4 or 2)
  __shared__ bf16 As[TM * 32];
  __shared__ bf16 Bs[128 * 32];
  const int tid  = threadIdx.x;
  const int lane = tid & 63, wid = tid >> 6;
  const int qr   = lane & 15, quad = lane >> 4;
  const int wm   = wid >> 1, wn = wid & 1;
  const int bm   = blockIdx.x, bn = blockIdx.y, z = blockIdx.z;
  const int kbeg = z * Kc;
  const int kend = min(K, kbeg + Kc);
  const int sr   = wid * 16 + (lane >> 2);  // staging row 0..63
  const int scol = (lane & 3) * 8;          // staging col (elems)

  f32x4 zero4 = {0.f, 0.f, 0.f, 0.f};
  f32x4 acc[MI][4];
#pragma unroll
  for (int i = 0; i < MI; i++)
#pragma unroll
    for (int j = 0; j < 4; j++) acc[i][j] = zero4;

  int ra[TM / 64];
#pragma unroll
  for (int s = 0; s < TM / 64; s++)
    ra[s] = min(bm * TM + s * 64 + sr, M - 1);      // clamp ragged M
  const size_t nr0 = (size_t)(bn * 128 + sr);
  const size_t nr1 = (size_t)(bn * 128 + 64 + sr);

  for (int k0 = kbeg; k0 < kend; k0 += 32) {
    __syncthreads();
#pragma unroll
    for (int s = 0; s < TM / 64; s++)
      async_ld16(A + (size_t)ra[s] * K + k0 + scol, &As[(s * 64 + wid * 16) * 32]);
    async_ld16(Wt + nr0 * K + k0 + scol, &Bs[(wid * 16) * 32]);
    async_ld16(Wt + nr1 * K + k0 + scol, &Bs[(64 + wid * 16) * 32]);
    __syncthreads();
    bf16x8 af[MI], bfr[4];
#pragma unroll
    for (int mi = 0; mi < MI; mi++)
      af[mi] = *(const bf16x8*)&As[(wm * (MI * 16) + mi * 16 + qr) * 32 + quad * 8];
#pragma unroll
    for (int ni = 0; ni < 4; ni++)
      bfr[ni] = *(const bf16x8*)&Bs[(wn * 64 + ni * 16 + qr) * 32 + quad * 8];
#pragma unroll
    for (int mi = 0; mi < MI; mi++)
#pragma unroll
      for (int ni = 0; ni < 4; ni++)
        acc[mi][ni] = MFMA16(af[mi], bfr[ni], acc[mi][ni]);
  }

  // epilogue: C row = quad*4+r, col = lane&15 within each 16x16 tile
#pragma unroll
  for (int mi = 0; mi < MI; mi++) {
#pragma unroll
    for (int ni = 0; ni < 4; ni++) {
      const int row0 = bm * TM + wm * (MI * 16) + mi * 16 + quad * 4;
      const int col  = bn * 128 + wn * 64 + ni * 16 + qr;
      const float bv = (z == 0) ? bias[col] : 0.f;
#pragma unroll
      for (int r = 0; r < 4; r++) {
        const int row = row0 + r;
        if (row < M) {
          float v = acc[mi][ni][r] + bv;
          if constexpr (EPI == EPI_PATCH) {
            int bb = row / 196, nn = row % 196;
            int orow = bb * 197 + 1 + nn;
            atomicAdd(&outF[(size_t)orow * 768 + col], v);
          } else if constexpr (EPI == EPI_BF16) {
            outB[(size_t)row * N + col] = (bf16)v;
          } else if constexpr (EPI == EPI_GELU) {
            float gel = 0.5f * v * (1.f + erff(v * 0.70710678118f));
            outB[(size_t)row * N + col] = (bf16)gel;
          } else {  // EPI_RESID: h += (acc + bias)
            atomicAdd(&outF[(size_t)row * 768 + col], v);
          }
        }
      }
    }
  }
}

// ---------------- 8-wave, 128 x 128 (wide-N GEMMs: QKV, FC1) ----------------
// Per-wave 32x64 tile -> acc = 32 AGPR; total regs ~85 <= 128 -> 4 waves/SIMD,
// 16 waves/CU (2 blocks) instead of the 4-wave kernel's 8 waves/CU.
template <int EPI>
__global__ __launch_bounds__(512, 4) void gemm_bt8(
    const bf16* __restrict__ A, const bf16* __restrict__ Wt,
    const float* __restrict__ bias, bf16* __restrict__ outB,
    int M, int N, int K)
{
  __shared__ bf16 As[128 * 32];
  __shared__ bf16 Bs[128 * 32];
  const int tid  = threadIdx.x;
  const int lane = tid & 63, wid = tid >> 6;       // wid 0..7
  const int qr   = lane & 15, quad = lane >> 4;
  const int wm   = wid >> 1, wn = wid & 1;         // wm 0..3, wn 0..1
  const int bm   = blockIdx.x, bn = blockIdx.y;
  const int sr   = wid * 16 + (lane >> 2);         // staging row 0..127
  const int scol = (lane & 3) * 8;

  f32x4 zero4 = {0.f, 0.f, 0.f, 0.f};
  f32x4 acc[2][4];
#pragma unroll
  for (int i = 0; i < 2; i++)
#pragma unroll
    for (int j = 0; j < 4; j++) acc[i][j] = zero4;

  const int ra = min(bm * 128 + sr, M - 1);
  const size_t nr = (size_t)(bn * 128 + sr);

  for (int k0 = 0; k0 < K; k0 += 32) {
    __syncthreads();
    async_ld16(A  + (size_t)ra * K + k0 + scol, &As[(wid * 16) * 32]);
    async_ld16(Wt + nr * K + k0 + scol,         &Bs[(wid * 16) * 32]);
    __syncthreads();
    bf16x8 af[2], bfr[4];
#pragma unroll
    for (int mi = 0; mi < 2; mi++)
      af[mi] = *(const bf16x8*)&As[(wm * 32 + mi * 16 + qr) * 32 + quad * 8];
#pragma unroll
    for (int ni = 0; ni < 4; ni++)
      bfr[ni] = *(const bf16x8*)&Bs[(wn * 64 + ni * 16 + qr) * 32 + quad * 8];
#pragma unroll
    for (int mi = 0; mi < 2; mi++)
#pragma unroll
      for (int ni = 0; ni < 4; ni++)
        acc[mi][ni] = MFMA16(af[mi], bfr[ni], acc[mi][ni]);
  }

#pragma unroll
  for (int mi = 0; mi < 2; mi++) {
#pragma unroll
    for (int ni = 0; ni < 4; ni++) {
      const int row0 = bm * 128 + wm * 32 + mi * 16 + quad * 4;
      const int col  = bn * 128 + wn * 64 + ni * 16 + qr;
      const float bv = bias[col];
#pragma unroll
      for (int r = 0; r < 4; r++) {
        const int row = row0 + r;
        if (row < M) {
          float v = acc[mi][ni][r] + bv;
          if constexpr (EPI == EPI_GELU) {
            float gel = 0.5f * v * (1.f + erff(v * 0.70710678118f));
            outB[(size_t)row * N + col] = (bf16)gel;
          } else {
            outB[(size_t)row * N + col] = (bf16)v;
          }
        }
      }
    }
  }
}

// Attention: one block = (b, head, 64 q-rows). Full K/V in LDS. S=197, dh=64.
// P aliases K's LDS (K dead after scores) -> 67 KB -> 2 blocks/CU.
__global__ __launch_bounds__(256) void attn_kernel(
    const bf16* __restrict__ qkv, bf16* __restrict__ o)
{
  __shared__ __align__(16) char smem[68864];
  bf16 (*Qs)[72]  = (bf16(*)[72])(smem);                 //  9216 B
  bf16 (*Ks)[72]  = (bf16(*)[72])(smem + 9216);          // 29952 B
  bf16 (*Ps)[232] = (bf16(*)[232])(smem + 9216);         // aliases Ks (29696 B)
  bf16 (*Vt)[232] = (bf16(*)[232])(smem + 39168);        // 29696 B

  const int tid  = threadIdx.x;
  const int lane = tid & 63, wid = tid >> 6;
  const int qr   = lane & 15, quad = lane >> 4;
  const int qt   = blockIdx.x & 3, bh = blockIdx.x >> 2;
  const int head = bh % 12, b = bh / 12;
  const int q0   = qt * 64;
  const size_t base = (size_t)b * 197 * 2304 + head * 64;

  // stage Q (clamp rows >196 to 196; garbage rows never stored)
  {
    int r = tid >> 2, cb = (tid & 3) * 16;
    int s = q0 + r; if (s > 196) s = 196;
    const bf16* src = qkv + base + (size_t)s * 2304 + cb;
    *(uint4*)&Qs[r][cb]     = *(const uint4*)src;
    *(uint4*)&Qs[r][cb + 8] = *(const uint4*)(src + 8);
  }
  // stage K rows 0..207 (zeros >=197)
  for (int rr = tid >> 2; rr < 208; rr += 64) {
    int cb = (tid & 3) * 16;
    uint4 v0 = make_uint4(0, 0, 0, 0), v1 = make_uint4(0, 0, 0, 0);
    if (rr < 197) {
      const bf16* src = qkv + base + 768 + (size_t)rr * 2304 + cb;
      v0 = *(const uint4*)src; v1 = *(const uint4*)(src + 8);
    }
    *(uint4*)&Ks[rr][cb] = v0; *(uint4*)&Ks[rr][cb + 8] = v1;
  }
  // stage V transposed [d][key] (zeros for key>=197)
  for (int rr = tid >> 2; rr < 224; rr += 64) {
    int cb = (tid & 3) * 16;
    bf16 tmp[16];
    if (rr < 197) {
      const bf16* src = qkv + base + 1536 + (size_t)rr * 2304 + cb;
      *(uint4*)&tmp[0] = *(const uint4*)src;
      *(uint4*)&tmp[8] = *(const uint4*)(src + 8);
    } else {
#pragma unroll
      for (int j = 0; j < 16; j++) tmp[j] = (bf16)0.f;
    }
#pragma unroll
    for (int j = 0; j < 16; j++) Vt[cb + j][rr] = tmp[j];
  }
  __syncthreads();

  // scores: wave handles q rows [wid*16, wid*16+16)
  bf16x8 qa0 = *(const bf16x8*)&Qs[wid * 16 + qr][quad * 8];
  bf16x8 qa1 = *(const bf16x8*)&Qs[wid * 16 + qr][32 + quad * 8];
  f32x4 zero4 = {0.f, 0.f, 0.f, 0.f};
  f32x4 sc[13];
#pragma unroll
  for (int t = 0; t < 13; t++) sc[t] = zero4;
#pragma unroll
  for (int t = 0; t < 13; t++) {
    bf16x8 kb0 = *(const bf16x8*)&Ks[t * 16 + qr][quad * 8];
    bf16x8 kb1 = *(const bf16x8*)&Ks[t * 16 + qr][32 + quad * 8];
    sc[t] = MFMA16(qa0, kb0, sc[t]);
    sc[t] = MFMA16(qa1, kb1, sc[t]);
  }
  // softmax: lane holds col=16t+qr, row=quad*4+r; row-reduce across 16 lanes
  float mx[4] = {-1e30f, -1e30f, -1e30f, -1e30f};
#pragma unroll
  for (int t = 0; t < 13; t++) {
    bool valid = (t * 16 + qr) < 197;
#pragma unroll
    for (int r = 0; r < 4; r++) {
      float v = sc[t][r] * 0.125f;
      sc[t][r] = v;
      if (valid) mx[r] = fmaxf(mx[r], v);
    }
  }
#pragma unroll
  for (int r = 0; r < 4; r++)
#pragma unroll
    for (int off = 1; off < 16; off <<= 1)
      mx[r] = fmaxf(mx[r], __shfl_xor(mx[r], off, 16));
  float sum[4] = {0.f, 0.f, 0.f, 0.f};
#pragma unroll
  for (int t = 0; t < 13; t++) {
    bool valid = (t * 16 + qr) < 197;
#pragma unroll
    for (int r = 0; r < 4; r++) {
      float e = valid ? __expf(sc[t][r] - mx[r]) : 0.f;
      sc[t][r] = e; sum[r] += e;
    }
  }
#pragma unroll
  for (int r = 0; r < 4; r++) {
#pragma unroll
    for (int off = 1; off < 16; off <<= 1)
      sum[r] += __shfl_xor(sum[r], off, 16);
    sum[r] = 1.f / sum[r];
  }
  __syncthreads();   // all waves done reading Ks; safe to overwrite with Ps
#pragma unroll
  for (int t = 0; t < 13; t++)
#pragma unroll
    for (int r = 0; r < 4; r++)
      Ps[wid * 16 + quad * 4 + r][t * 16 + qr] = (bf16)(sc[t][r] * sum[r]);
  // zero Ps pad cols [208,224): wave covers its own 16 rows
  {
    bf16x4 zz = {(bf16)0.f, (bf16)0.f, (bf16)0.f, (bf16)0.f};
    *(bf16x4*)&Ps[wid * 16 + qr][208 + quad * 4] = zz;
  }
  __syncthreads();

  // PV: O[64 x 64] per wave-tile; K-loop over padded 224 keys
  f32x4 oa[4];
#pragma unroll
  for (int ni = 0; ni < 4; ni++) oa[ni] = zero4;
#pragma unroll
  for (int k0 = 0; k0 < 224; k0 += 32) {
    bf16x8 pa = *(const bf16x8*)&Ps[wid * 16 + qr][k0 + quad * 8];
#pragma unroll
    for (int ni = 0; ni < 4; ni++) {
      bf16x8 vb = *(const bf16x8*)&Vt[ni * 16 + qr][k0 + quad * 8];
      oa[ni] = MFMA16(pa, vb, oa[ni]);
    }
  }
  // store O at [b][s][head][d]
#pragma unroll
  for (int ni = 0; ni < 4; ni++)
#pragma unroll
    for (int r = 0; r < 4; r++) {
      int row = q0 + wid * 16 + quad * 4 + r;
      if (row < 197)
        o[(((size_t)b * 197 + row) * 12 + head) * 64 + ni * 16 + qr] =
            (bf16)oa[ni][r];
    }
}

// LayerNorm over 768, one wave per row, bf16 out
__global__ __launch_bounds__(256) void ln_bf16(
    const float* __restrict__ h, const float* __restrict__ w,
    const float* __restrict__ b, bf16* __restrict__ y, int rows)
{
  int row = blockIdx.x * 4 + (threadIdx.x >> 6);
  int lane = threadIdx.x & 63;
  if (row >= rows) return;
  const float* hr = h + (size_t)row * 768;
  float v[12]; float s = 0.f;
#pragma unroll
  for (int i = 0; i < 12; i++) { v[i] = hr[lane + 64 * i]; s += v[i]; }
#pragma unroll
  for (int off = 32; off >= 1; off >>= 1) s += __shfl_xor(s, off, 64);
  float mean = s * (1.f / 768.f);
  float q = 0.f;
#pragma unroll
  for (int i = 0; i < 12; i++) { float d = v[i] - mean; q += d * d; }
#pragma unroll
  for (int off = 32; off >= 1; off >>= 1) q += __shfl_xor(q, off, 64);
  float rstd = rsqrtf(q * (1.f / 768.f) + 1e-6f);
  bf16* yr = y + (size_t)row * 768;
#pragma unroll
  for (int i = 0; i < 12; i++)
    yr[lane + 64 * i] = (bf16)((v[i] - mean) * rstd * w[lane + 64 * i] + b[lane + 64 * i]);
}

// Final LN on the 32 CLS rows, fp32 out
__global__ __launch_bounds__(256) void ln_final(
    const float* __restrict__ h, const float* __restrict__ w,
    const float* __restrict__ b, float* __restrict__ out)
{
  int bi = blockIdx.x * 4 + (threadIdx.x >> 6);
  int lane = threadIdx.x & 63;
  if (bi >= 32) return;
  const float* hr = h + (size_t)bi * 197 * 768;
  float v[12]; float s = 0.f;
#pragma unroll
  for (int i = 0; i < 12; i++) { v[i] = hr[lane + 64 * i]; s += v[i]; }
#pragma unroll
  for (int off = 32; off >= 1; off >>= 1) s += __shfl_xor(s, off, 64);
  float mean = s * (1.f / 768.f);
  float q = 0.f;
#pragma unroll
  for (int i = 0; i < 12; i++) { float d = v[i] - mean; q += d * d; }
#pragma unroll
  for (int off = 32; off >= 1; off >>= 1) q += __shfl_xor(q, off, 64);
  float rstd = rsqrtf(q * (1.f / 768.f) + 1e-6f);
#pragma unroll
  for (int i = 0; i < 12; i++)
    out[(size_t)bi * 768 + lane + 64 * i] =
        (v[i] - mean) * rstd * w[lane + 64 * i] + b[lane + 64 * i];
}

// [z][R][C] fp32 -> [z][C][R] bf16 (all dims multiples of 32)
__global__ __launch_bounds__(256) void transpose_w(
    const float* __restrict__ in, bf16* __restrict__ out, int R, int C)
{
  __shared__ float t[32][33];
  size_t zoff = (size_t)blockIdx.z * R * C;
  in += zoff; out += zoff;
  int c0 = blockIdx.x * 32, r0 = blockIdx.y * 32;
  int lx = threadIdx.x & 31, ly = threadIdx.x >> 5;  // 32 x 8
#pragma unroll
  for (int i = 0; i < 32; i += 8) t[ly + i][lx] = in[(size_t)(r0 + ly + i) * C + c0 + lx];
  __syncthreads();
#pragma unroll
  for (int i = 0; i < 32; i += 8)
    out[(size_t)(c0 + ly + i) * R + r0 + lx] = (bf16)t[lx][ly + i];
}

__global__ __launch_bounds__(256) void convert_bf16(
    const float* __restrict__ in, bf16* __restrict__ out, int n)
{
  int i = blockIdx.x * 256 + threadIdx.x;
  if (i < n) out[i] = (bf16)in[i];
}

// x(32,3,224,224) -> patches[6272][768] bf16; k = c*256 + iy*16 + ix
__global__ __launch_bounds__(256) void patch_extract(
    const float* __restrict__ x, bf16* __restrict__ patches)
{
  int i = blockIdx.x * 256 + threadIdx.x;
  if (i >= 6272 * 192) return;
  int m = i / 192, kq = (i % 192) * 4;
  int b = m / 196, pp = m % 196, py = pp / 14, px = pp % 14;
  int c = kq >> 8, rem = kq & 255, iy = rem >> 4, ix = rem & 15;
  const float4 v = *(const float4*)&x[(((size_t)(b * 3 + c) * 224 + py * 16 + iy) * 224) + px * 16 + ix];
  bf16x4 pv = {(bf16)v.x, (bf16)v.y, (bf16)v.z, (bf16)v.w};
  *(bf16x4*)&patches[(size_t)m * 768 + kq] = pv;
}

// prefill h: h[b][s][:] = pos[s] (+ cls for s==0); patch GEMM then accumulates
__global__ __launch_bounds__(256) void h_init_full(
    const float* __restrict__ cls, const float* __restrict__ pos,
    float* __restrict__ h)
{
  int i = blockIdx.x * 256 + threadIdx.x;
  if (i >= 6304 * 192) return;
  int row = i / 192, c4 = (i % 192) * 4;
  int s = row % 197;
  float4 pv = *(const float4*)&pos[(size_t)s * 768 + c4];
  if (s == 0) {
    float4 cv = *(const float4*)&cls[c4];
    pv.x += cv.x; pv.y += cv.y; pv.z += cv.z; pv.w += cv.w;
  }
  *(float4*)&h[(size_t)row * 768 + c4] = pv;
}

extern "C" void kernel_launch(void* const* d_in, const int* in_sizes, int n_in,
                              void* d_out, int out_size, void* d_ws, size_t ws_size,
                              hipStream_t stream)
{
  const float* x      = (const float*)d_in[0];
  const float* conv_w = (const float*)d_in[1];
  const float* conv_b = (const float*)d_in[2];
  const float* cls    = (const float*)d_in[3];
  const float* pos    = (const float*)d_in[4];
  const float* ln1_w  = (const float*)d_in[5];
  const float* ln1_b  = (const float*)d_in[6];
  const float* qkv_w  = (const float*)d_in[7];
  const float* qkv_b  = (const float*)d_in[8];
  const float* proj_w = (const float*)d_in[9];
  const float* proj_b = (const float*)d_in[10];
  const float* ln2_w  = (const float*)d_in[11];
  const float* ln2_b  = (const float*)d_in[12];
  const float* fc1_w  = (const float*)d_in[13];
  const float* fc1_b  = (const float*)d_in[14];
  const float* fc2_w  = (const float*)d_in[15];
  const float* fc2_b  = (const float*)d_in[16];
  const float* lnf_w  = (const float*)d_in[17];
  const float* lnf_b  = (const float*)d_in[18];
  float* out = (float*)d_out;
  (void)in_sizes; (void)n_in; (void)out_size; (void)ws_size;

  char* ws = (char*)d_ws;
  size_t off = 0;
  auto alloc = [&](size_t bytes) -> char* {
    char* p = ws + off;
    off += (bytes + 255) & ~(size_t)255;
    return p;
  };

  bf16*  convwB  = (bf16*)alloc((size_t)768 * 768 * 2);
  bf16*  qkvT    = (bf16*)alloc((size_t)12 * 2304 * 768 * 2);
  bf16*  projT   = (bf16*)alloc((size_t)12 * 768 * 768 * 2);
  bf16*  fc1T    = (bf16*)alloc((size_t)12 * 3072 * 768 * 2);
  bf16*  fc2T    = (bf16*)alloc((size_t)12 * 768 * 3072 * 2);
  bf16*  patches = (bf16*)alloc((size_t)6272 * 768 * 2);
  float* h       = (float*)alloc((size_t)6304 * 768 * 4);
  bf16*  y       = (bf16*)alloc((size_t)6304 * 768 * 2);
  bf16*  qkvB    = (bf16*)alloc((size_t)6304 * 2304 * 2);
  bf16*  obuf    = (bf16*)alloc((size_t)6304 * 768 * 2);
  bf16*  g       = (bf16*)alloc((size_t)6304 * 3072 * 2);

  // weight prep (every call: ws is re-poisoned)
  convert_bf16<<<(768 * 768 + 255) / 256, 256, 0, stream>>>(conv_w, convwB, 768 * 768);
  transpose_w<<<dim3(2304 / 32, 768 / 32, 12), 256, 0, stream>>>(qkv_w, qkvT, 768, 2304);
  transpose_w<<<dim3(768 / 32, 768 / 32, 12), 256, 0, stream>>>(proj_w, projT, 768, 768);
  transpose_w<<<dim3(3072 / 32, 768 / 32, 12), 256, 0, stream>>>(fc1_w, fc1T, 768, 3072);
  transpose_w<<<dim3(768 / 32, 3072 / 32, 12), 256, 0, stream>>>(fc2_w, fc2T, 3072, 768);

  patch_extract<<<(6272 * 192) / 256, 256, 0, stream>>>(x, patches);
  h_init_full<<<(6304 * 192 + 255) / 256, 256, 0, stream>>>(cls, pos, h);
  gemm_bt<EPI_PATCH, 64><<<dim3(98, 6, 1), 256, 0, stream>>>(
      patches, convwB, conv_b, nullptr, h, 6272, 768, 768, 768);

  for (int l = 0; l < 12; l++) {
    ln_bf16<<<1576, 256, 0, stream>>>(h, ln1_w + l * 768, ln1_b + l * 768, y, 6304);
    gemm_bt8<EPI_BF16><<<dim3(50, 18), 512, 0, stream>>>(
        y, qkvT + (size_t)l * 2304 * 768, qkv_b + l * 2304, qkvB,
        6304, 2304, 768);
    attn_kernel<<<32 * 12 * 4, 256, 0, stream>>>(qkvB, obuf);
    gemm_bt<EPI_RESID, 64><<<dim3(99, 6, 1), 256, 0, stream>>>(
        obuf, projT + (size_t)l * 768 * 768, proj_b + l * 768, nullptr, h,
        6304, 768, 768, 768);
    ln_bf16<<<1576, 256, 0, stream>>>(h, ln2_w + l * 768, ln2_b + l * 768, y, 6304);
    gemm_bt8<EPI_GELU><<<dim3(50, 24), 512, 0, stream>>>(
        y, fc1T + (size_t)l * 3072 * 768, fc1_b + l * 3072, g,
        6304, 3072, 768);
    gemm_bt<EPI_RESID, 64><<<dim3(99, 6, 2), 256, 0, stream>>>(
        g, fc2T + (size_t)l * 768 * 3072, fc2_b + l * 768, nullptr, h,
        6304, 768, 3072, 1536);
  }
  ln_final<<<8, 256, 0, stream>>>(h, lnf_w, lnf_b, out);
}